// Round 1
// baseline (42.312 us; speedup 1.0000x reference)
//
#include <hip/hip_runtime.h>
#include <math.h>

#define BATCH 16384
#define DIM   256
#define ZNEG  10

// One wave (64 lanes) per batch element. Lane i owns float4 [4i..4i+3] of the
// 256-dim row -> each doc-row gather is one fully-coalesced 1KB wave read.
__global__ __launch_bounds__(256) void nvsm_kernel(
    const float* __restrict__ query,
    const float* __restrict__ doc_emb,
    const int*   __restrict__ document,
    const int*   __restrict__ neg_sample,
    float*       __restrict__ out)
{
    const int wave = threadIdx.x >> 6;          // 0..3
    const int lane = threadIdx.x & 63;
    const int b    = (blockIdx.x << 2) + wave;  // grid sized exactly: b < BATCH

    const float4 q = reinterpret_cast<const float4*>(query + (size_t)b * DIM)[lane];

    // lanes 0..10 hold the 11 doc indices (0 = positive, 1..10 = negatives)
    int idx = 0;
    if (lane == 0)         idx = document[b];
    else if (lane <= ZNEG) idx = neg_sample[b * ZNEG + (lane - 1)];

    float posterm = 0.f, negacc = 0.f;
    #pragma unroll
    for (int z = 0; z <= ZNEG; ++z) {
        const int d = __shfl(idx, z);           // broadcast index z to all lanes
        const float4 v =
            reinterpret_cast<const float4*>(doc_emb + (size_t)d * DIM)[lane];
        float p = q.x * v.x + q.y * v.y + q.z * v.z + q.w * v.w;
        #pragma unroll
        for (int off = 32; off; off >>= 1)      // 64-lane butterfly reduce
            p += __shfl_xor(p, off);

        // numerically-stable sigmoid (matches jax.nn.sigmoid's two-sided form;
        // naive 1/(1+exp(-p)) overflows f32 for p < -88, and |p| can reach ~80)
        float s;
        if (p >= 0.f) {
            s = 1.f / (1.f + expf(-p));
        } else {
            const float e = expf(p);
            s = e / (1.f + e);
        }
        if (z == 0) posterm = logf(s);
        else        negacc += logf(1.f - s + 1e-40f);  // EPS exactly as reference
    }

    if (lane == 0) {
        // (Z+1)/(2Z) * (Z*pos + neg) = 0.55 * (10*pos + neg)
        out[b] = ((ZNEG + 1) / (2.0f * ZNEG)) * (ZNEG * posterm + negacc);
    }
}

extern "C" void kernel_launch(void* const* d_in, const int* in_sizes, int n_in,
                              void* d_out, int out_size, void* d_ws, size_t ws_size,
                              hipStream_t stream) {
    const float* query      = (const float*)d_in[0];
    const float* doc_emb    = (const float*)d_in[1];
    const int*   document   = (const int*)d_in[2];
    const int*   neg_sample = (const int*)d_in[3];
    float*       out        = (float*)d_out;

    nvsm_kernel<<<BATCH / 4, 256, 0, stream>>>(query, doc_emb, document, neg_sample, out);
}

// Round 2
// 41.029 us; speedup vs baseline: 1.0313x; 1.0313x over previous
//
#include <hip/hip_runtime.h>
#include <math.h>

#define BATCH 16384
#define DIM   256
#define ZNEG  10

// One wave (64 lanes) per batch element. Lane i owns float4 [4i..4i+3] of the
// 256-dim row -> each doc-row gather is one fully-coalesced 1KB wave read.
//
// __launch_bounds__(256, 8): 8 waves/EU caps the allocator at 64 VGPRs so we
// keep 32 waves/CU resident (the naive full-unroll schedule wants ~70 VGPRs,
// which falls off the 64-VGPR occupancy cliff to 4 waves/EU). The compiler
// software-pipelines the 11 row loads in smaller batches instead.
__global__ __launch_bounds__(256, 8) void nvsm_kernel(
    const float* __restrict__ query,
    const float* __restrict__ doc_emb,
    const int*   __restrict__ document,
    const int*   __restrict__ neg_sample,
    float*       __restrict__ out)
{
    const int wave = threadIdx.x >> 6;          // 0..3
    const int lane = threadIdx.x & 63;
    const int b    = (blockIdx.x << 2) + wave;  // grid sized exactly: b < BATCH

    const float4 q = reinterpret_cast<const float4*>(query + (size_t)b * DIM)[lane];

    // lanes 0..10 hold the 11 doc indices (0 = positive, 1..10 = negatives)
    int idx = 0;
    if (lane == 0)         idx = document[b];
    else if (lane <= ZNEG) idx = neg_sample[b * ZNEG + (lane - 1)];

    float posterm = 0.f, negacc = 0.f;
    #pragma unroll
    for (int z = 0; z <= ZNEG; ++z) {
        const int d = __shfl(idx, z);           // broadcast index z to all lanes
        const float4 v =
            reinterpret_cast<const float4*>(doc_emb + (size_t)d * DIM)[lane];
        float p = q.x * v.x + q.y * v.y + q.z * v.z + q.w * v.w;
        #pragma unroll
        for (int off = 32; off; off >>= 1)      // 64-lane butterfly reduce
            p += __shfl_xor(p, off);

        // numerically-stable sigmoid (matches jax.nn.sigmoid's two-sided form;
        // naive 1/(1+exp(-p)) overflows f32 for p < -88, and |p| can reach ~80)
        float s;
        if (p >= 0.f) {
            s = 1.f / (1.f + expf(-p));
        } else {
            const float e = expf(p);
            s = e / (1.f + e);
        }
        if (z == 0) posterm = logf(s);
        else        negacc += logf(1.f - s + 1e-40f);  // EPS exactly as reference
    }

    if (lane == 0) {
        // (Z+1)/(2Z) * (Z*pos + neg) = 0.55 * (10*pos + neg)
        out[b] = ((ZNEG + 1) / (2.0f * ZNEG)) * (ZNEG * posterm + negacc);
    }
}

extern "C" void kernel_launch(void* const* d_in, const int* in_sizes, int n_in,
                              void* d_out, int out_size, void* d_ws, size_t ws_size,
                              hipStream_t stream) {
    const float* query      = (const float*)d_in[0];
    const float* doc_emb    = (const float*)d_in[1];
    const int*   document   = (const int*)d_in[2];
    const int*   neg_sample = (const int*)d_in[3];
    float*       out        = (float*)d_out;

    nvsm_kernel<<<BATCH / 4, 256, 0, stream>>>(query, doc_emb, document, neg_sample, out);
}